// Round 2
// 350.457 us; speedup vs baseline: 1.0161x; 1.0161x over previous
//
#include <hip/hip_runtime.h>

#define Bdim 16
#define Tdim 1024
#define Hdim 256
#define Ldim 2048

typedef __attribute__((ext_vector_type(8))) short short8;    // 8 x bf16 (4 VGPR) MFMA frag
typedef __attribute__((ext_vector_type(4))) short short4_t;  // 8B LDS store
typedef __attribute__((ext_vector_type(16))) float floatx16; // 32x32 MFMA accumulator

__device__ __forceinline__ ushort f2bf(float x) {
    union { float f; unsigned u; } v; v.f = x;
    unsigned r = v.u + 0x7fffu + ((v.u >> 16) & 1u);  // round-to-nearest-even
    return (ushort)(r >> 16);
}
__device__ __forceinline__ float bf2f(ushort u) {
    union { unsigned u; float f; } v; v.u = ((unsigned)u) << 16;
    return v.f;
}
__device__ __forceinline__ short8 pack8(float4 a, float4 b) {
    short8 r;
    r[0] = (short)f2bf(a.x); r[1] = (short)f2bf(a.y); r[2] = (short)f2bf(a.z); r[3] = (short)f2bf(a.w);
    r[4] = (short)f2bf(b.x); r[5] = (short)f2bf(b.y); r[6] = (short)f2bf(b.z); r[7] = (short)f2bf(b.w);
    return r;
}

// fp32 (B,T,H) -> bf16 (B,T,H) and bf16 transposed (B,H,T). All global accesses 16B.
__global__ __launch_bounds__(256) void convert_kernel(
    const float* __restrict__ in, ushort* __restrict__ outN, ushort* __restrict__ outT) {
    __shared__ ushort lds[64][68];
    const int b = blockIdx.z, h0 = blockIdx.y * 64, t0 = blockIdx.x * 64;
    const int tid = threadIdx.x;
#pragma unroll
    for (int i = 0; i < 2; i++) {
        const int tt = tid + i * 256;
        const int r = tt >> 3, c = (tt & 7) * 8;
        const float4* src = (const float4*)(in + ((size_t)(b * Tdim + t0 + r)) * Hdim + h0 + c);
        short8 u = pack8(src[0], src[1]);
        *(short8*)(outN + ((size_t)(b * Tdim + t0 + r)) * Hdim + h0 + c) = u;
        short4_t lo = {u[0], u[1], u[2], u[3]}, hi = {u[4], u[5], u[6], u[7]};
        *(short4_t*)&lds[r][c] = lo;
        *(short4_t*)&lds[r][c + 4] = hi;
    }
    __syncthreads();
#pragma unroll
    for (int i = 0; i < 2; i++) {
        const int tt = tid + i * 256;
        const int hh = tt >> 3, c = (tt & 7) * 8;
        short8 u;
#pragma unroll
        for (int j = 0; j < 8; j++) u[j] = (short)lds[c + j][hh];
        *(short8*)(outT + ((size_t)(b * Hdim + h0 + hh)) * Tdim + t0 + c) = u;
    }
}

// One block = (b, 32 L-rows), 8 waves, 32x32x16 MFMA.
// XCD swizzle: 2 batches per XCD -> K/V working set ~1 MB fits per-XCD L2.
//
// v2: kernel was latency-bound (MfmaUtil 8.5, VALUBusy 7.2, HBM 15%, Occ 38%).
// Full 32x1024 bf16 P in LDS (66 KB) capped occupancy at 2 blocks/CU.
// Now P is never fully materialized: each wave keeps its exp(S) strip packed in
// 32 VGPRs; Phase C runs over 4 chunks of 256 t with a double-buffered 32x264
// LDS chunk pair (34 KB total). Attention-out is written straight from
// registers (normalized dword stores, 128B/inst), saving the LDS round-trip.
// Chunk producers run one phase ahead of consumers. Occupancy now register-
// capped (~128 unified VGPR+AGPR/wave -> 4 waves/SIMD), not LDS-capped.
__global__ __launch_bounds__(512, 4) void attn_kernel(
    const float* __restrict__ table, const int* __restrict__ labels,
    const ushort* __restrict__ kn, const ushort* __restrict__ vt,
    float* __restrict__ logits_out, float* __restrict__ attn_out) {
    __shared__ ushort bufs[2][32][264];  // 33792 B; +8 pad: 132 dw/row == 4 mod 32 -> balanced b128
    __shared__ float stats[8][32];       // per-wave partial row sums
    float* rowinv = &stats[0][0];

    const int bid = blockIdx.x;
    const int xcd = bid & 7, w = bid >> 3;     // assume dispatch XCD = blockIdx % 8
    const int b = xcd * 2 + (w >> 6);          // 2 batches pinned per XCD
    const int l0 = (w & 63) * 32;
    const int tid = threadIdx.x;
    const int wave = tid >> 6, lane = tid & 63;
    const int half = lane >> 5, m = lane & 31;

    // Q tile aliases buf0 (dead before any strip write; barrier-protected)
    ushort (*qt)[264] = bufs[0];

    // ---- stage Q: gather 32 table rows, convert bf16 -> LDS ----
    {
        const int row = tid >> 4, cc = (tid & 15) * 16;
        const int lab = labels[b * Ldim + l0 + row];
        const float4* src = (const float4*)(table + (size_t)lab * Hdim + cc);
        float4 f0 = src[0], f1 = src[1], f2 = src[2], f3 = src[3];
        *(short8*)&qt[row][cc] = pack8(f0, f1);
        *(short8*)&qt[row][cc + 8] = pack8(f2, f3);
    }
    __syncthreads();

    // ---- Phase A: S-strip (32 l x 128 t) per wave, 4 independent chains ----
    floatx16 acc[4];
#pragma unroll
    for (int nt = 0; nt < 4; nt++)
#pragma unroll
        for (int r = 0; r < 16; r++) acc[nt][r] = 0.f;
    {
        const int t0s = wave * 128;
        const ushort* kb = kn + ((size_t)(b * Tdim + t0s + m)) * Hdim + half * 8;
        const ushort* qb = &qt[m][half * 8];
#pragma unroll
        for (int ks = 0; ks < 16; ks++) {
            short8 af = *(const short8*)(qb + ks * 16);
            short8 b0 = *(const short8*)(kb + ks * 16);
            short8 b1 = *(const short8*)(kb + 32 * Hdim + ks * 16);
            short8 b2 = *(const short8*)(kb + 64 * Hdim + ks * 16);
            short8 b3 = *(const short8*)(kb + 96 * Hdim + ks * 16);
            acc[0] = __builtin_amdgcn_mfma_f32_32x32x16_bf16(af, b0, acc[0], 0, 0, 0);
            acc[1] = __builtin_amdgcn_mfma_f32_32x32x16_bf16(af, b1, acc[1], 0, 0, 0);
            acc[2] = __builtin_amdgcn_mfma_f32_32x32x16_bf16(af, b2, acc[2], 0, 0, 0);
            acc[3] = __builtin_amdgcn_mfma_f32_32x32x16_bf16(af, b3, acc[3], 0, 0, 0);
        }
    }

    // ---- exp + per-row sums. 32x32 C/D: row=(r&3)+8*(r>>2)+4*half, col=m ----
    float rs[16];
#pragma unroll
    for (int nt = 0; nt < 4; nt++)
#pragma unroll
        for (int r = 0; r < 16; r++) {
            float e = __expf(acc[nt][r]);
            acc[nt][r] = e;
            if (nt == 0) rs[r] = e; else rs[r] += e;
        }
#pragma unroll
    for (int s = 1; s < 32; s <<= 1)
#pragma unroll
        for (int r = 0; r < 16; r++) rs[r] += __shfl_xor(rs[r], s, 64);
    if (m == 0) {
#pragma unroll
        for (int r = 0; r < 16; r++) stats[wave][(r & 3) + 8 * (r >> 2) + 4 * half] = rs[r];
    }
    __syncthreads();  // Phase A done everywhere: Q region dead, stats visible

    if (tid < 32) {
        float d = 0.f;
#pragma unroll
        for (int wv = 0; wv < 8; wv++) d += stats[wv][tid];
        rowinv[tid] = 1.0f / d;  // aliases stats[0]; own slot read before write
    }

    // ---- pack exp(S) strip to bf16 pairs: pk[p][r] = {bf16(acc[2p][r]), bf16(acc[2p+1][r])} ----
    unsigned pk[2][16];
#pragma unroll
    for (int p = 0; p < 2; p++)
#pragma unroll
        for (int r = 0; r < 16; r++)
            pk[p][r] = (unsigned)f2bf(acc[2 * p][r]) |
                       ((unsigned)f2bf(acc[2 * p + 1][r]) << 16);

    // wave w's strip lives in chunk (w>>1), column half (w&1)*128 of the chunk buffer
    const int coff = (wave & 1) * 128;
    auto write_strip = [&](int bi) {
        ushort(*dst)[264] = bufs[bi];
#pragma unroll
        for (int p = 0; p < 2; p++)
#pragma unroll
            for (int r = 0; r < 16; r++) {
                const int row = (r & 3) + 8 * (r >> 2) + 4 * half;
                dst[row][coff + (2 * p) * 32 + m] = (ushort)(pk[p][r] & 0xffffu);
                dst[row][coff + (2 * p + 1) * 32 + m] = (ushort)(pk[p][r] >> 16);
            }
    };

    if ((wave >> 1) == 0) write_strip(0);
    __syncthreads();  // buf0 ready, rowinv visible

    // ---- attention out: straight from registers, normalized, 128B/inst dword stores ----
    {
        float inv[16];
#pragma unroll
        for (int r = 0; r < 16; r++) inv[r] = rowinv[(r & 3) + 8 * (r >> 2) + 4 * half];
        float* dst = attn_out + ((size_t)(b * Ldim + l0)) * Tdim + wave * 128 + m;
#pragma unroll
        for (int p = 0; p < 2; p++)
#pragma unroll
            for (int r = 0; r < 16; r++) {
                const int row = (r & 3) + 8 * (r >> 2) + 4 * half;
                dst[(size_t)row * Tdim + (2 * p) * 32] =
                    bf2f((ushort)(pk[p][r] & 0xffffu)) * inv[r];
                dst[(size_t)row * Tdim + (2 * p + 1) * 32] =
                    bf2f((ushort)(pk[p][r] >> 16)) * inv[r];
            }
    }

    // ---- Phase C: logits = P.V over 4 chunks of 256 t, producers one phase ahead ----
    {
        floatx16 c0, c1;
#pragma unroll
        for (int r = 0; r < 16; r++) { c0[r] = 0.f; c1[r] = 0.f; }
        const int h0 = wave * 32;
        const ushort* vb = vt + ((size_t)(b * Hdim + h0 + m)) * Tdim + half * 8;
#pragma unroll
        for (int c = 0; c < 4; c++) {
            if (c) __syncthreads();  // prev chunk reads done; this chunk's writes visible
            if (c < 3 && (wave >> 1) == c + 1) write_strip((c + 1) & 1);
            const ushort* pb = &bufs[c & 1][m][half * 8];
            const ushort* vc = vb + c * 256;
#pragma unroll
            for (int ks = 0; ks < 8; ks++) {
                short8 a0 = *(const short8*)(pb + (2 * ks) * 16);
                short8 v0 = *(const short8*)(vc + (2 * ks) * 16);
                c0 = __builtin_amdgcn_mfma_f32_32x32x16_bf16(a0, v0, c0, 0, 0, 0);
                short8 a1 = *(const short8*)(pb + (2 * ks + 1) * 16);
                short8 v1 = *(const short8*)(vc + (2 * ks + 1) * 16);
                c1 = __builtin_amdgcn_mfma_f32_32x32x16_bf16(a1, v1, c1, 0, 0, 0);
            }
        }
#pragma unroll
        for (int r = 0; r < 16; r++) {
            const int row = (r & 3) + 8 * (r >> 2) + 4 * half;
            logits_out[((size_t)(b * Ldim + l0 + row)) * Hdim + h0 + m] =
                (c0[r] + c1[r]) * rowinv[row];
        }
    }
}

extern "C" void kernel_launch(void* const* d_in, const int* in_sizes, int n_in,
                              void* d_out, int out_size, void* d_ws, size_t ws_size,
                              hipStream_t stream) {
    const float* inputs = (const float*)d_in[0];   // (B,T,H) fp32
    const int* labels   = (const int*)d_in[1];     // (B,L)
    const float* table  = (const float*)d_in[2];   // (NC+1,H) fp32
    float* out = (float*)d_out;

    ushort* kn = (ushort*)d_ws;                    // bf16 (B,T,H)
    ushort* vt = kn + (size_t)Bdim * Tdim * Hdim;  // bf16 (B,H,T)

    convert_kernel<<<dim3(Tdim / 64, Hdim / 64, Bdim), 256, 0, stream>>>(inputs, kn, vt);

    float* logits_out = out;
    float* attn_out = out + (size_t)Bdim * Ldim * Hdim;
    attn_kernel<<<Bdim * (Ldim / 32), 512, 0, stream>>>(table, labels, kn, vt,
                                                        logits_out, attn_out);
}